// Round 5
// baseline (7811.739 us; speedup 1.0000x reference)
//
#include <hip/hip_runtime.h>
#include <hip/hip_bf16.h>

#define Bsz 256
#define Tlen 512
#define Dd 512
#define Hh 1024
#define G4 4096
#define NOUT 8
#define BT (Bsz * Tlen)

typedef short s16x8 __attribute__((ext_vector_type(8)));
typedef unsigned short u16x8 __attribute__((ext_vector_type(8)));
typedef float f32x4 __attribute__((ext_vector_type(4)));

__device__ __forceinline__ ushort f2bf(float f) {
    union { float f; uint u; } v; v.f = f;
    uint u = v.u;
    uint r = u + 0x7FFFu + ((u >> 16) & 1u);   // round-to-nearest-even
    return (ushort)(r >> 16);
}
__device__ __forceinline__ float bf2f(ushort u) {
    union { uint u; float f; } v; v.u = ((uint)u) << 16; return v.f;
}
__device__ __forceinline__ float sigf(float x) { return 1.f / (1.f + __expf(-x)); }
__device__ __forceinline__ float tanhfast(float x) {
    float ax = fabsf(x);
    float e = __expf(-2.f * ax);
    float t = (1.f - e) / (1.f + e);
    return copysignf(t, x);
}

// ---------------- init: zero h0 (bf16, buffer 0) and c (fp32) ----------------
__global__ void init_kernel(uint4* __restrict__ h0, uint4* __restrict__ c) {
    int i = blockIdx.x * 256 + threadIdx.x;       // 65536 threads
    uint4 z = make_uint4(0u, 0u, 0u, 0u);
    c[i] = z;                                     // 1 MB
    if (i < 32768) h0[i] = z;                     // 512 KB
}

// ---------------- fp32 -> bf16 convert (layout-preserving) ----------------
__global__ void cvt_kernel(const float4* __restrict__ src, ushort4* __restrict__ dst, int n4) {
    int i = blockIdx.x * 256 + threadIdx.x;
    if (i >= n4) return;
    float4 v = src[i];
    ushort4 o;
    o.x = f2bf(v.x); o.y = f2bf(v.y); o.z = f2bf(v.z); o.w = f2bf(v.w);
    dst[i] = o;
}

// ---------------- chunk convert: x[:, t0..t0+7, :] fp32 -> [256][8][512] bf16 ----------------
__global__ void cvt_xchunk(const float* __restrict__ x, ushort* __restrict__ dst, int t0) {
    int gid = blockIdx.x * 256 + threadIdx.x;     // 131072 units of 8 elems
    int k8  = gid & 63;
    int tl  = (gid >> 6) & 7;
    int row = gid >> 9;                           // 0..255
    const float* s = x + ((size_t)row * Tlen + t0 + tl) * Dd + k8 * 8;
    float4 v0 = *(const float4*)s;
    float4 v1 = *(const float4*)(s + 4);
    u16x8 o;
    o[0]=f2bf(v0.x); o[1]=f2bf(v0.y); o[2]=f2bf(v0.z); o[3]=f2bf(v0.w);
    o[4]=f2bf(v1.x); o[5]=f2bf(v1.y); o[6]=f2bf(v1.z); o[7]=f2bf(v1.w);
    *(u16x8*)(dst + ((size_t)row * 8 + tl) * Dd + k8 * 8) = o;
}

// ---------------- one LSTM time step: barrier-free K-loop ----------------
// 256 blocks x 512 threads (8 waves, 2/SIMD). Block -> (bt, jt) XCD-remap.
// Output tile: 64 batch rows x 64 gate-cols {g*1024 + jt*16 + cv}.
// Wave w owns K-slice [w*192, (w+1)*192) = chunks {3w, 3w+1, 3w+2} of 64.
// A (x|h rows) and B (W cols) fragments loaded GLOBAL->REG directly; the
// compiler pipelines the 3 chunks with its own counted vmcnt; zero barriers
// until the single partial-reduce sync. 8 partial 64x64 f32 tiles in LDS.
__launch_bounds__(512, 2)
__global__ void lstm_step4(const ushort* __restrict__ xsrc, int tstride, int tloc,
                           const ushort* __restrict__ Wih,   // bf16 [4096][512]
                           const ushort* __restrict__ Whh,   // bf16 [4096][1024]
                           const ushort* __restrict__ h_prev,// bf16 [256][1024]
                           ushort* __restrict__ h_next,
                           float* __restrict__ c,            // fp32 [256][1024]
                           const float* __restrict__ b_ih,
                           const float* __restrict__ b_hh) {
    __shared__ float part[8][64 * 68];    // 139264 B
    __shared__ float bias_lds[64];

    const int tid  = threadIdx.x;
    const int lane = tid & 63;
    const int w    = tid >> 6;           // 0..7
    const int B    = blockIdx.x;
    const int xcd  = B & 7, slot = B >> 3;     // XCD remap: 4 bt-copies of a jt share an XCD
    const int jt   = xcd * 8 + (slot >> 2);    // 0..63
    const int bt   = slot & 3;                 // 0..3
    const int b0   = bt * 64;

    if (tid < 64) {
        int gcol = (tid >> 4) * 1024 + jt * 16 + (tid & 15);
        bias_lds[tid] = b_ih[gcol] + b_hh[gcol];
    }

    const int rlo = lane & 15;           // row/col within a 16-tile
    const int k8  = (lane >> 4) << 3;    // k sub-offset 0,8,16,24

    auto loadA = [&](s16x8 (&a)[4][2], int cidx) {
        const int kc = cidx << 6;
        #pragma unroll
        for (int ks = 0; ks < 2; ++ks) {
            const int k = kc + (ks << 5) + k8;
            #pragma unroll
            for (int m = 0; m < 4; ++m) {
                const int row = b0 + (m << 4) + rlo;
                const ushort* p = (k < Dd)
                    ? xsrc + ((size_t)row * tstride + tloc) * Dd + k
                    : h_prev + (size_t)row * Hh + (k - Dd);
                a[m][ks] = *(const s16x8*)p;
            }
        }
    };
    auto loadB = [&](s16x8 (&b)[4][2], int cidx) {
        const int kc = cidx << 6;
        #pragma unroll
        for (int ks = 0; ks < 2; ++ks) {
            const int k = kc + (ks << 5) + k8;
            #pragma unroll
            for (int n = 0; n < 4; ++n) {
                const int grow = (n << 10) + (jt << 4) + rlo;
                const ushort* p = (k < Dd)
                    ? Wih + (size_t)grow * Dd + k
                    : Whh + (size_t)grow * Hh + (k - Dd);
                b[n][ks] = *(const s16x8*)p;
            }
        }
    };

    f32x4 acc[4][4] = {};
    auto MFMA = [&](s16x8 (&a)[4][2], s16x8 (&b)[4][2]) {
        #pragma unroll
        for (int ks = 0; ks < 2; ++ks)
            #pragma unroll
            for (int m = 0; m < 4; ++m)
                #pragma unroll
                for (int n = 0; n < 4; ++n)
                    acc[m][n] = __builtin_amdgcn_mfma_f32_16x16x32_bf16(a[m][ks], b[n][ks], acc[m][n], 0, 0, 0);
    };

    const int ch0 = w * 3;
    s16x8 aA[4][2], bA[4][2], aB[4][2], bB[4][2];
    loadA(aA, ch0);     loadB(bA, ch0);
    loadA(aB, ch0 + 1); loadB(bB, ch0 + 1);
    MFMA(aA, bA);
    loadA(aA, ch0 + 2); loadB(bA, ch0 + 2);
    MFMA(aB, bB);
    MFMA(aA, bA);

    // ---- partial tile -> LDS (bank-checked: 2 lanes/bank, free) ----
    float* bw = part[w];
    #pragma unroll
    for (int m = 0; m < 4; ++m)
        #pragma unroll
        for (int n = 0; n < 4; ++n)
            #pragma unroll
            for (int j = 0; j < 4; ++j) {
                int row = (m << 4) + ((lane >> 4) << 2) + j;
                int col = (n << 4) + rlo;
                bw[row * 68 + col] = acc[m][n][j];
            }
    __syncthreads();

    // ---- reduce 8 partials + activations + cell update ----
    // thread -> cells (row = (tid>>4)*2 + u, cv = tid&15): conflict-free LDS
    const int cv = tid & 15;
    const int r0 = (tid >> 4) << 1;
    #pragma unroll
    for (int u = 0; u < 2; ++u) {
        const int row = r0 + u;
        float gi = bias_lds[cv],      gf = bias_lds[16 + cv];
        float gg = bias_lds[32 + cv], go = bias_lds[48 + cv];
        #pragma unroll
        for (int p = 0; p < 8; ++p) {
            const float* bb = part[p] + row * 68;
            gi += bb[cv]; gf += bb[16 + cv]; gg += bb[32 + cv]; go += bb[48 + cv];
        }
        float i_ = sigf(gi), f_ = sigf(gf), g_ = tanhfast(gg), o_ = sigf(go);
        const int gcol = (jt << 4) + cv;
        const size_t cidx = (size_t)(b0 + row) * Hh + gcol;
        float cn = f_ * c[cidx] + i_ * g_;
        c[cidx] = cn;
        h_next[cidx] = f2bf(o_ * tanhfast(cn));
    }
}

// ---------------- FALLBACK: proven round-0 fused step ----------------
__launch_bounds__(256)
__global__ void lstm_step_fused(const float* __restrict__ x,
                          const ushort* __restrict__ Wih,
                          const ushort* __restrict__ Whh,
                          const float* __restrict__ b_ih,
                          const float* __restrict__ b_hh,
                          const ushort* __restrict__ h_prev,
                          ushort* __restrict__ h_next,
                          float* __restrict__ c,
                          int t) {
    __shared__ ushort At[64 * 64];
    __shared__ ushort Bt[64 * 64];
    __shared__ float gates[64 * 72];

    const int tid  = threadIdx.x;
    const int lane = tid & 63;
    const int wid  = tid >> 6;
    const int wr   = wid >> 1;
    const int wc   = wid & 1;
    const int bt   = blockIdx.x >> 6;
    const int jt   = blockIdx.x & 63;
    const int b0   = bt * 64;
    const int j0   = jt * 16;

    f32x4 acc[2][2] = {};

    auto mfma_tile = [&]() {
        #pragma unroll
        for (int ks = 0; ks < 2; ++ks) {
            const int kc = (ks << 2) + (lane >> 4);
            s16x8 a[2], bfr[2];
            #pragma unroll
            for (int m = 0; m < 2; ++m) {
                int row = wr * 32 + m * 16 + (lane & 15);
                a[m] = *(const s16x8*)&At[row * 64 + ((kc ^ (row & 7)) << 3)];
            }
            #pragma unroll
            for (int n = 0; n < 2; ++n) {
                int col = wc * 32 + n * 16 + (lane & 15);
                bfr[n] = *(const s16x8*)&Bt[col * 64 + ((kc ^ (col & 7)) << 3)];
            }
            #pragma unroll
            for (int m = 0; m < 2; ++m)
                #pragma unroll
                for (int n = 0; n < 2; ++n)
                    acc[m][n] = __builtin_amdgcn_mfma_f32_16x16x32_bf16(a[m], bfr[n], acc[m][n], 0, 0, 0);
        }
    };

    for (int kb = 0; kb < Dd; kb += 64) {
        __syncthreads();
        #pragma unroll
        for (int it = 0; it < 4; ++it) {
            int idx = tid + it * 256;
            int row = idx >> 4;
            int k   = (idx & 15) * 4;
            const float4 v = *(const float4*)&x[(size_t)(b0 + row) * (Tlen * Dd) + (size_t)t * Dd + kb + k];
            ushort4 o;
            o.x = f2bf(v.x); o.y = f2bf(v.y); o.z = f2bf(v.z); o.w = f2bf(v.w);
            int dst = row * 64 + (((k >> 3) ^ (row & 7)) << 3) + (k & 7);
            *(ushort4*)&At[dst] = o;
        }
        #pragma unroll
        for (int it = 0; it < 2; ++it) {
            int idx = tid + it * 256;
            int col = idx >> 3;
            int kc  = idx & 7;
            int grow = ((col >> 4) << 10) + j0 + (col & 15);
            uint4 v = *(const uint4*)&Wih[(size_t)grow * Dd + kb + kc * 8];
            *(uint4*)&Bt[col * 64 + ((kc ^ (col & 7)) << 3)] = v;
        }
        __syncthreads();
        mfma_tile();
    }
    for (int kb = 0; kb < Hh; kb += 64) {
        __syncthreads();
        #pragma unroll
        for (int it = 0; it < 2; ++it) {
            int idx = tid + it * 256;
            int row = idx >> 3;
            int kc  = idx & 7;
            uint4 v = *(const uint4*)&h_prev[(size_t)(b0 + row) * Hh + kb + kc * 8];
            *(uint4*)&At[row * 64 + ((kc ^ (row & 7)) << 3)] = v;
        }
        #pragma unroll
        for (int it = 0; it < 2; ++it) {
            int idx = tid + it * 256;
            int col = idx >> 3;
            int kc  = idx & 7;
            int grow = ((col >> 4) << 10) + j0 + (col & 15);
            uint4 v = *(const uint4*)&Whh[(size_t)grow * Hh + kb + kc * 8];
            *(uint4*)&Bt[col * 64 + ((kc ^ (col & 7)) << 3)] = v;
        }
        __syncthreads();
        mfma_tile();
    }

    #pragma unroll
    for (int m = 0; m < 2; ++m)
        #pragma unroll
        for (int n = 0; n < 2; ++n)
            #pragma unroll
            for (int j = 0; j < 4; ++j) {
                int row = wr * 32 + m * 16 + ((lane >> 4) << 2) + j;
                int col = wc * 32 + n * 16 + (lane & 15);
                gates[row * 72 + col] = acc[m][n][j];
            }
    __syncthreads();

    #pragma unroll
    for (int it = 0; it < 4; ++it) {
        int idx = tid + it * 256;
        int row = idx >> 4;
        int cc  = idx & 15;
        int gcol = j0 + cc;
        float gi = gates[row * 72 + cc]      + b_ih[gcol]          + b_hh[gcol];
        float gf = gates[row * 72 + 16 + cc] + b_ih[Hh + gcol]     + b_hh[Hh + gcol];
        float gg = gates[row * 72 + 32 + cc] + b_ih[2 * Hh + gcol] + b_hh[2 * Hh + gcol];
        float go = gates[row * 72 + 48 + cc] + b_ih[3 * Hh + gcol] + b_hh[3 * Hh + gcol];
        float i_ = sigf(gi);
        float f_ = sigf(gf);
        float g_ = tanhfast(gg);
        float o_ = sigf(go);
        size_t cidx = (size_t)(b0 + row) * Hh + gcol;
        float cn = f_ * c[cidx] + i_ * g_;
        c[cidx] = cn;
        float hn = o_ * tanhfast(cn);
        h_next[cidx] = f2bf(hn);
    }
}

// ---------------- FC head ----------------
__global__ void fc_kernel(const ushort* __restrict__ h,
                          const float* __restrict__ Wfc,
                          const float* __restrict__ bfc,
                          float* __restrict__ out) {
    int b = blockIdx.x;
    int w = threadIdx.x >> 6;
    int lane = threadIdx.x & 63;
    float s = 0.f;
    for (int k = lane; k < Hh; k += 64)
        s += bf2f(h[(size_t)b * Hh + k]) * Wfc[w * Hh + k];
    #pragma unroll
    for (int off = 32; off; off >>= 1) s += __shfl_down(s, off);
    if (lane == 0) out[b * NOUT + w] = sigf(s + bfc[w]);
}

// ================= LAUNCH =================

extern "C" void kernel_launch(void* const* d_in, const int* in_sizes, int n_in,
                              void* d_out, int out_size, void* d_ws, size_t ws_size,
                              hipStream_t stream) {
    const float* x    = (const float*)d_in[0];
    const float* W_ih = (const float*)d_in[1];
    const float* W_hh = (const float*)d_in[2];
    const float* b_ih = (const float*)d_in[3];
    const float* b_hh = (const float*)d_in[4];
    const float* W_fc = (const float*)d_in[5];
    const float* b_fc = (const float*)d_in[6];
    float* out = (float*)d_out;
    char* ws = (char*)d_ws;

    // ws layout (fixed part = 14 MB, proven available):
    //   [0, 1 MB)    h ping-pong bf16 [2][256][1024]
    //   [1, 2 MB)    c fp32 [256][1024]
    //   [2, 6 MB)    W_ih bf16 [4096][512]
    //   [6, 14 MB)   W_hh bf16 [4096][1024]
    //   [14 MB, ..)  x bf16: full [256][512][512] (128 MB, T1) or
    //                2 chunk buffers [256][8][512] (4 MB, T2)
    ushort* h_buf  = (ushort*)ws;
    float*  c_ws   = (float*)(ws + (1ull << 20));
    ushort* wih_bf = (ushort*)(ws + (2ull << 20));
    ushort* whh_bf = (ushort*)(ws + (6ull << 20));
    char*   x_ext  = ws + (14ull << 20);

    const size_t FIXED   = 14ull << 20;
    const size_t XFULL   = (size_t)Bsz * Tlen * Dd * 2;        // 128 MB
    const size_t XCHUNK  = (size_t)Bsz * 8 * Dd * 2;           // 2 MB per buffer

    init_kernel<<<256, 256, 0, stream>>>((uint4*)h_buf, (uint4*)c_ws);
    cvt_kernel<<<(G4 * Dd / 4) / 256, 256, 0, stream>>>((const float4*)W_ih, (ushort4*)wih_bf, G4 * Dd / 4);
    cvt_kernel<<<(G4 * Hh / 4) / 256, 256, 0, stream>>>((const float4*)W_hh, (ushort4*)whh_bf, G4 * Hh / 4);

    if (ws_size >= FIXED + XFULL) {
        // T1: convert all of x once; layout [b][t][k] (tstride=512)
        ushort* x_bf = (ushort*)x_ext;
        const int n4 = BT * Dd / 4;
        cvt_kernel<<<n4 / 256, 256, 0, stream>>>((const float4*)x, (ushort4*)x_bf, n4);
        for (int t = 0; t < Tlen; ++t) {
            const ushort* hp = h_buf + (size_t)(t & 1) * Bsz * Hh;
            ushort*       hn = h_buf + (size_t)((t + 1) & 1) * Bsz * Hh;
            lstm_step4<<<256, 512, 0, stream>>>(x_bf, Tlen, t, wih_bf, whh_bf,
                                                hp, hn, c_ws, b_ih, b_hh);
        }
    } else if (ws_size >= FIXED + 2 * XCHUNK) {
        // T2: double-buffered 8-step chunks; layout [b][8][k] (tstride=8)
        ushort* xchunk = (ushort*)x_ext;
        for (int t = 0; t < Tlen; ++t) {
            if ((t & 7) == 0) {
                ushort* dst = xchunk + (size_t)((t >> 3) & 1) * (Bsz * 8 * Dd);
                cvt_xchunk<<<512, 256, 0, stream>>>(x, dst, t);
            }
            const ushort* xb = xchunk + (size_t)((t >> 3) & 1) * (Bsz * 8 * Dd);
            const ushort* hp = h_buf + (size_t)(t & 1) * Bsz * Hh;
            ushort*       hn = h_buf + (size_t)((t + 1) & 1) * Bsz * Hh;
            lstm_step4<<<256, 512, 0, stream>>>(xb, 8, t & 7, wih_bf, whh_bf,
                                                hp, hn, c_ws, b_ih, b_hh);
        }
    } else {
        // T3: proven fallback
        for (int t = 0; t < Tlen; ++t) {
            const ushort* hp = h_buf + (size_t)(t & 1) * Bsz * Hh;
            ushort*       hn = h_buf + (size_t)((t + 1) & 1) * Bsz * Hh;
            lstm_step_fused<<<256, 256, 0, stream>>>(x, wih_bf, whh_bf, b_ih, b_hh, hp, hn, c_ws, t);
        }
    }
    // 512 steps (even) -> final h in buffer 0
    fc_kernel<<<256, 512, 0, stream>>>(h_buf, W_fc, b_fc, out);
}

// Round 6
// 6539.987 us; speedup vs baseline: 1.1945x; 1.1945x over previous
//
#include <hip/hip_runtime.h>
#include <hip/hip_bf16.h>

#define Bsz 256
#define Tlen 512
#define Dd 512
#define Hh 1024
#define G4 4096
#define NOUT 8
#define BT (Bsz * Tlen)

typedef short s16x8 __attribute__((ext_vector_type(8)));
typedef unsigned short u16x8 __attribute__((ext_vector_type(8)));
typedef float f32x4 __attribute__((ext_vector_type(4)));

__device__ __forceinline__ ushort f2bf(float f) {
    union { float f; uint u; } v; v.f = f;
    uint u = v.u;
    uint r = u + 0x7FFFu + ((u >> 16) & 1u);   // round-to-nearest-even
    return (ushort)(r >> 16);
}
__device__ __forceinline__ float bf2f(ushort u) {
    union { uint u; float f; } v; v.u = ((uint)u) << 16; return v.f;
}
__device__ __forceinline__ float sigf(float x) { return 1.f / (1.f + __expf(-x)); }
__device__ __forceinline__ float tanhfast(float x) {
    float ax = fabsf(x);
    float e = __expf(-2.f * ax);
    float t = (1.f - e) / (1.f + e);
    return copysignf(t, x);
}
__device__ __forceinline__ void gload16(const void* g, void* l) {
    __builtin_amdgcn_global_load_lds(
        (const __attribute__((address_space(1))) uint*)g,
        (__attribute__((address_space(3))) uint*)l, 16, 0, 0);
}

// ---------------- init: zero h0 (bf16, buffer 0) and c (fp32) ----------------
__global__ void init_kernel(uint4* __restrict__ h0, uint4* __restrict__ c) {
    int i = blockIdx.x * 256 + threadIdx.x;       // 65536 threads
    uint4 z = make_uint4(0u, 0u, 0u, 0u);
    c[i] = z;                                     // 1 MB
    if (i < 32768) h0[i] = z;                     // 512 KB
}

// ---------------- fp32 -> bf16 convert (layout-preserving) ----------------
__global__ void cvt_kernel(const float4* __restrict__ src, ushort4* __restrict__ dst, int n4) {
    int i = blockIdx.x * 256 + threadIdx.x;
    if (i >= n4) return;
    float4 v = src[i];
    ushort4 o;
    o.x = f2bf(v.x); o.y = f2bf(v.y); o.z = f2bf(v.z); o.w = f2bf(v.w);
    dst[i] = o;
}

// ---------------- chunk convert: x[:, t0..t0+7, :] fp32 -> [256][8][512] bf16 ----------------
__global__ void cvt_xchunk(const float* __restrict__ x, ushort* __restrict__ dst, int t0) {
    int gid = blockIdx.x * 256 + threadIdx.x;     // 131072 units of 8 elems
    int k8  = gid & 63;
    int tl  = (gid >> 6) & 7;
    int row = gid >> 9;                           // 0..255
    const float* s = x + ((size_t)row * Tlen + t0 + tl) * Dd + k8 * 8;
    float4 v0 = *(const float4*)s;
    float4 v1 = *(const float4*)(s + 4);
    u16x8 o;
    o[0]=f2bf(v0.x); o[1]=f2bf(v0.y); o[2]=f2bf(v0.z); o[3]=f2bf(v0.w);
    o[4]=f2bf(v1.x); o[5]=f2bf(v1.y); o[6]=f2bf(v1.z); o[7]=f2bf(v1.w);
    *(u16x8*)(dst + ((size_t)row * 8 + tl) * Dd + k8 * 8) = o;
}

// ---------------- one LSTM time step: counted-vmcnt pipeline, single K-group ----
// 256 blocks x 512 threads (8 waves). Block -> (bt, jt) XCD-remap.
// Output tile 64 batch rows x 64 gate-cols; 16 MFMA-tiles over 8 waves = 2/wave
// (wave w: m = w&3, n in {2*(w>>2), 2*(w>>2)+1}) -> each wave owns full K for
// its tiles: NO partial reduction. K loop: 12 iters of K=128, LDS dbuf
// 2 x (A 16KB + B 16KB). Per iter, HK-style sync (T3+T4):
//   STAGE(next) ; s_waitcnt vmcnt(4) ; s_barrier ; COMPUTE(cur) ;
//   s_waitcnt lgkmcnt(0) ; s_barrier            -- no full vmcnt drain.
__launch_bounds__(512, 2)
__global__ void lstm_step5(const ushort* __restrict__ xsrc, int tstride, int tloc,
                           const ushort* __restrict__ Wih,   // bf16 [4096][512]
                           const ushort* __restrict__ Whh,   // bf16 [4096][1024]
                           const ushort* __restrict__ h_prev,// bf16 [256][1024]
                           ushort* __restrict__ h_next,
                           float* __restrict__ c,            // fp32 [256][1024]
                           const float* __restrict__ b_ih,
                           const float* __restrict__ b_hh) {
    __shared__ char smem[65536];          // 2 bufs x (A 16KB + B 16KB)
    __shared__ float bias_lds[64];

    const int tid  = threadIdx.x;
    const int lane = tid & 63;
    const int w    = tid >> 6;            // 0..7
    const int mw   = w & 3;               // A row-tile
    const int nh   = w >> 2;              // B col-tile pair
    const int B    = blockIdx.x;
    const int xcd  = B & 7, slot = B >> 3;      // XCD remap: 4 bt-copies of a jt share an XCD
    const int jt   = xcd * 8 + (slot >> 2);     // 0..63
    const int bt   = slot & 3;                  // 0..3
    const int b0   = bt * 64;

    if (tid < 64) {
        int gcol = (tid >> 4) * 1024 + jt * 16 + (tid & 15);
        bias_lds[tid] = b_ih[gcol] + b_hh[gcol];
    }

    const int rlo = lane & 15;

    // stage chunk ch (k = ch*128 .. +128) into buf. 4 gload_lds per wave.
    // LDS linear [64 rows][16 chunks of 16B]; global source chunk pre-swizzled
    // cs = slot ^ (row&7) so swizzled ds_read gets linear k (rule #21).
    auto STAGE = [&](int buf, int ch) {
        const int k0 = ch << 7;
        char* Abase = smem + buf * 32768;
        char* Bbase = Abase + 16384;
        #pragma unroll
        for (int i = 0; i < 2; ++i) {
            const int ii  = (w << 1) + i;          // 0..15, wave-uniform
            const int row = (ii << 2) + (lane >> 4);
            const int cs  = (lane & 15) ^ (row & 7);
            const int k   = k0 + cs * 8;
            // A: rows = batch rows (x for ch<4, h for ch>=4)
            {
                const ushort* p = (k0 < Dd)
                    ? xsrc + ((size_t)(b0 + row) * tstride + tloc) * Dd + k
                    : h_prev + (size_t)(b0 + row) * Hh + (k - Dd);
                gload16(p, Abase + ii * 1024);
            }
            // B: cols = gate cols, grow = (col>>4)*1024 + jt*16 + (col&15)
            {
                const int grow = ((row >> 4) << 10) + (jt << 4) + (row & 15);
                const ushort* p = (k0 < Dd)
                    ? Wih + (size_t)grow * Dd + k
                    : Whh + (size_t)grow * Hh + (k - Dd);
                gload16(p, Bbase + ii * 1024);
            }
        }
    };

    f32x4 acc[2] = {};
    auto COMPUTE = [&](int buf) {
        const char* Ab = smem + buf * 32768;
        const char* Bb = Ab + 16384;
        const int arow  = (mw << 4) + rlo;
        const int bcol0 = (nh << 5) + rlo;
        #pragma unroll
        for (int ks = 0; ks < 4; ++ks) {
            const int kc = (ks << 2) + (lane >> 4);
            s16x8 a  = *(const s16x8*)(Ab + arow * 256 + ((kc ^ (arow & 7)) << 4));
            s16x8 b0v = *(const s16x8*)(Bb + bcol0 * 256 + ((kc ^ (bcol0 & 7)) << 4));
            s16x8 b1v = *(const s16x8*)(Bb + (bcol0 + 16) * 256 + ((kc ^ (bcol0 & 7)) << 4));
            acc[0] = __builtin_amdgcn_mfma_f32_16x16x32_bf16(a, b0v, acc[0], 0, 0, 0);
            acc[1] = __builtin_amdgcn_mfma_f32_16x16x32_bf16(a, b1v, acc[1], 0, 0, 0);
        }
    };

    STAGE(0, 0);                                   // 4 outstanding
    #pragma unroll
    for (int ch = 0; ch < 12; ++ch) {
        const int cb = ch & 1;
        if (ch < 11) {
            STAGE(cb ^ 1, ch + 1);                 // +4 -> 8 outstanding
            __builtin_amdgcn_sched_barrier(0);
            asm volatile("s_waitcnt vmcnt(4)" ::: "memory");   // cur landed, next in flight
        } else {
            asm volatile("s_waitcnt vmcnt(0)" ::: "memory");
        }
        __builtin_amdgcn_s_barrier();              // all waves' cur loads landed
        __builtin_amdgcn_sched_barrier(0);
        COMPUTE(cb);
        asm volatile("s_waitcnt lgkmcnt(0)" ::: "memory");     // my ds_reads done
        __builtin_amdgcn_s_barrier();              // buf reusable for staging
    }

    // ---- epilogue: acc -> gates LDS (reuse buf0 region), activations ----
    float* gates = (float*)smem;                   // [64][68] = 17.4 KB
    {
        const int q = (lane >> 4) << 2;
        #pragma unroll
        for (int n = 0; n < 2; ++n) {
            const int col = ((nh << 1) + n) * 16 + rlo;
            #pragma unroll
            for (int j = 0; j < 4; ++j) {
                const int row = (mw << 4) + q + j;
                gates[row * 68 + col] = acc[n][j];
            }
        }
    }
    __syncthreads();

    const int cv = tid & 15;
    const int r0 = (tid >> 4) << 1;
    #pragma unroll
    for (int u = 0; u < 2; ++u) {
        const int row = r0 + u;
        const float* gr = gates + row * 68;
        float gi = gr[cv]      + bias_lds[cv];
        float gf = gr[16 + cv] + bias_lds[16 + cv];
        float gg = gr[32 + cv] + bias_lds[32 + cv];
        float go = gr[48 + cv] + bias_lds[48 + cv];
        float i_ = sigf(gi), f_ = sigf(gf), g_ = tanhfast(gg), o_ = sigf(go);
        const int gcol = (jt << 4) + cv;
        const size_t cidx = (size_t)(b0 + row) * Hh + gcol;
        float cn = f_ * c[cidx] + i_ * g_;
        c[cidx] = cn;
        h_next[cidx] = f2bf(o_ * tanhfast(cn));
    }
}

// ---------------- FALLBACK: proven round-0 fused step ----------------
__launch_bounds__(256)
__global__ void lstm_step_fused(const float* __restrict__ x,
                          const ushort* __restrict__ Wih,
                          const ushort* __restrict__ Whh,
                          const float* __restrict__ b_ih,
                          const float* __restrict__ b_hh,
                          const ushort* __restrict__ h_prev,
                          ushort* __restrict__ h_next,
                          float* __restrict__ c,
                          int t) {
    __shared__ ushort At[64 * 64];
    __shared__ ushort Bt[64 * 64];
    __shared__ float gates[64 * 72];

    const int tid  = threadIdx.x;
    const int lane = tid & 63;
    const int wid  = tid >> 6;
    const int wr   = wid >> 1;
    const int wc   = wid & 1;
    const int bt   = blockIdx.x >> 6;
    const int jt   = blockIdx.x & 63;
    const int b0   = bt * 64;
    const int j0   = jt * 16;

    f32x4 acc[2][2] = {};

    auto mfma_tile = [&]() {
        #pragma unroll
        for (int ks = 0; ks < 2; ++ks) {
            const int kc = (ks << 2) + (lane >> 4);
            s16x8 a[2], bfr[2];
            #pragma unroll
            for (int m = 0; m < 2; ++m) {
                int row = wr * 32 + m * 16 + (lane & 15);
                a[m] = *(const s16x8*)&At[row * 64 + ((kc ^ (row & 7)) << 3)];
            }
            #pragma unroll
            for (int n = 0; n < 2; ++n) {
                int col = wc * 32 + n * 16 + (lane & 15);
                bfr[n] = *(const s16x8*)&Bt[col * 64 + ((kc ^ (col & 7)) << 3)];
            }
            #pragma unroll
            for (int m = 0; m < 2; ++m)
                #pragma unroll
                for (int n = 0; n < 2; ++n)
                    acc[m][n] = __builtin_amdgcn_mfma_f32_16x16x32_bf16(a[m], bfr[n], acc[m][n], 0, 0, 0);
        }
    };

    for (int kb = 0; kb < Dd; kb += 64) {
        __syncthreads();
        #pragma unroll
        for (int it = 0; it < 4; ++it) {
            int idx = tid + it * 256;
            int row = idx >> 4;
            int k   = (idx & 15) * 4;
            const float4 v = *(const float4*)&x[(size_t)(b0 + row) * (Tlen * Dd) + (size_t)t * Dd + kb + k];
            ushort4 o;
            o.x = f2bf(v.x); o.y = f2bf(v.y); o.z = f2bf(v.z); o.w = f2bf(v.w);
            int dst = row * 64 + (((k >> 3) ^ (row & 7)) << 3) + (k & 7);
            *(ushort4*)&At[dst] = o;
        }
        #pragma unroll
        for (int it = 0; it < 2; ++it) {
            int idx = tid + it * 256;
            int col = idx >> 3;
            int kc  = idx & 7;
            int grow = ((col >> 4) << 10) + j0 + (col & 15);
            uint4 v = *(const uint4*)&Wih[(size_t)grow * Dd + kb + kc * 8];
            *(uint4*)&Bt[col * 64 + ((kc ^ (col & 7)) << 3)] = v;
        }
        __syncthreads();
        mfma_tile();
    }
    for (int kb = 0; kb < Hh; kb += 64) {
        __syncthreads();
        #pragma unroll
        for (int it = 0; it < 2; ++it) {
            int idx = tid + it * 256;
            int row = idx >> 3;
            int kc  = idx & 7;
            uint4 v = *(const uint4*)&h_prev[(size_t)(b0 + row) * Hh + kb + kc * 8];
            *(uint4*)&At[row * 64 + ((kc ^ (row & 7)) << 3)] = v;
        }
        #pragma unroll
        for (int it = 0; it < 2; ++it) {
            int idx = tid + it * 256;
            int col = idx >> 3;
            int kc  = idx & 7;
            int grow = ((col >> 4) << 10) + j0 + (col & 15);
            uint4 v = *(const uint4*)&Whh[(size_t)grow * Hh + kb + kc * 8];
            *(uint4*)&Bt[col * 64 + ((kc ^ (col & 7)) << 3)] = v;
        }
        __syncthreads();
        mfma_tile();
    }

    #pragma unroll
    for (int m = 0; m < 2; ++m)
        #pragma unroll
        for (int n = 0; n < 2; ++n)
            #pragma unroll
            for (int j = 0; j < 4; ++j) {
                int row = wr * 32 + m * 16 + ((lane >> 4) << 2) + j;
                int col = wc * 32 + n * 16 + (lane & 15);
                gates[row * 72 + col] = acc[m][n][j];
            }
    __syncthreads();

    #pragma unroll
    for (int it = 0; it < 4; ++it) {
        int idx = tid + it * 256;
        int row = idx >> 4;
        int cc  = idx & 15;
        int gcol = j0 + cc;
        float gi = gates[row * 72 + cc]      + b_ih[gcol]          + b_hh[gcol];
        float gf = gates[row * 72 + 16 + cc] + b_ih[Hh + gcol]     + b_hh[Hh + gcol];
        float gg = gates[row * 72 + 32 + cc] + b_ih[2 * Hh + gcol] + b_hh[2 * Hh + gcol];
        float go = gates[row * 72 + 48 + cc] + b_ih[3 * Hh + gcol] + b_hh[3 * Hh + gcol];
        float i_ = sigf(gi);
        float f_ = sigf(gf);
        float g_ = tanhfast(gg);
        float o_ = sigf(go);
        size_t cidx = (size_t)(b0 + row) * Hh + gcol;
        float cn = f_ * c[cidx] + i_ * g_;
        c[cidx] = cn;
        float hn = o_ * tanhfast(cn);
        h_next[cidx] = f2bf(hn);
    }
}

// ---------------- FC head ----------------
__global__ void fc_kernel(const ushort* __restrict__ h,
                          const float* __restrict__ Wfc,
                          const float* __restrict__ bfc,
                          float* __restrict__ out) {
    int b = blockIdx.x;
    int w = threadIdx.x >> 6;
    int lane = threadIdx.x & 63;
    float s = 0.f;
    for (int k = lane; k < Hh; k += 64)
        s += bf2f(h[(size_t)b * Hh + k]) * Wfc[w * Hh + k];
    #pragma unroll
    for (int off = 32; off; off >>= 1) s += __shfl_down(s, off);
    if (lane == 0) out[b * NOUT + w] = sigf(s + bfc[w]);
}

// ================= LAUNCH =================

extern "C" void kernel_launch(void* const* d_in, const int* in_sizes, int n_in,
                              void* d_out, int out_size, void* d_ws, size_t ws_size,
                              hipStream_t stream) {
    const float* x    = (const float*)d_in[0];
    const float* W_ih = (const float*)d_in[1];
    const float* W_hh = (const float*)d_in[2];
    const float* b_ih = (const float*)d_in[3];
    const float* b_hh = (const float*)d_in[4];
    const float* W_fc = (const float*)d_in[5];
    const float* b_fc = (const float*)d_in[6];
    float* out = (float*)d_out;
    char* ws = (char*)d_ws;

    // ws layout (fixed part = 14 MB, proven available):
    //   [0, 1 MB)    h ping-pong bf16 [2][256][1024]
    //   [1, 2 MB)    c fp32 [256][1024]
    //   [2, 6 MB)    W_ih bf16 [4096][512]
    //   [6, 14 MB)   W_hh bf16 [4096][1024]
    //   [14 MB, ..)  x bf16: full [256][512][512] (128 MB, T1) or
    //                2 chunk buffers [256][8][512] (4 MB, T2)
    ushort* h_buf  = (ushort*)ws;
    float*  c_ws   = (float*)(ws + (1ull << 20));
    ushort* wih_bf = (ushort*)(ws + (2ull << 20));
    ushort* whh_bf = (ushort*)(ws + (6ull << 20));
    char*   x_ext  = ws + (14ull << 20);

    const size_t FIXED   = 14ull << 20;
    const size_t XFULL   = (size_t)Bsz * Tlen * Dd * 2;        // 128 MB
    const size_t XCHUNK  = (size_t)Bsz * 8 * Dd * 2;           // 2 MB per buffer

    init_kernel<<<256, 256, 0, stream>>>((uint4*)h_buf, (uint4*)c_ws);
    cvt_kernel<<<(G4 * Dd / 4) / 256, 256, 0, stream>>>((const float4*)W_ih, (ushort4*)wih_bf, G4 * Dd / 4);
    cvt_kernel<<<(G4 * Hh / 4) / 256, 256, 0, stream>>>((const float4*)W_hh, (ushort4*)whh_bf, G4 * Hh / 4);

    if (ws_size >= FIXED + XFULL) {
        // T1: convert all of x once; layout [b][t][k] (tstride=512)
        ushort* x_bf = (ushort*)x_ext;
        const int n4 = BT * Dd / 4;
        cvt_kernel<<<n4 / 256, 256, 0, stream>>>((const float4*)x, (ushort4*)x_bf, n4);
        for (int t = 0; t < Tlen; ++t) {
            const ushort* hp = h_buf + (size_t)(t & 1) * Bsz * Hh;
            ushort*       hn = h_buf + (size_t)((t + 1) & 1) * Bsz * Hh;
            lstm_step5<<<256, 512, 0, stream>>>(x_bf, Tlen, t, wih_bf, whh_bf,
                                                hp, hn, c_ws, b_ih, b_hh);
        }
    } else if (ws_size >= FIXED + 2 * XCHUNK) {
        // T2: double-buffered 8-step chunks; layout [b][8][k] (tstride=8)
        ushort* xchunk = (ushort*)x_ext;
        for (int t = 0; t < Tlen; ++t) {
            if ((t & 7) == 0) {
                ushort* dst = xchunk + (size_t)((t >> 3) & 1) * (Bsz * 8 * Dd);
                cvt_xchunk<<<512, 256, 0, stream>>>(x, dst, t);
            }
            const ushort* xb = xchunk + (size_t)((t >> 3) & 1) * (Bsz * 8 * Dd);
            const ushort* hp = h_buf + (size_t)(t & 1) * Bsz * Hh;
            ushort*       hn = h_buf + (size_t)((t + 1) & 1) * Bsz * Hh;
            lstm_step5<<<256, 512, 0, stream>>>(xb, 8, t & 7, wih_bf, whh_bf,
                                                hp, hn, c_ws, b_ih, b_hh);
        }
    } else {
        // T3: proven fallback
        for (int t = 0; t < Tlen; ++t) {
            const ushort* hp = h_buf + (size_t)(t & 1) * Bsz * Hh;
            ushort*       hn = h_buf + (size_t)((t + 1) & 1) * Bsz * Hh;
            lstm_step_fused<<<256, 256, 0, stream>>>(x, wih_bf, whh_bf, b_ih, b_hh, hp, hn, c_ws, t);
        }
    }
    // 512 steps (even) -> final h in buffer 0
    fc_kernel<<<256, 512, 0, stream>>>(h_buf, W_fc, b_fc, out);
}

// Round 7
// 6134.407 us; speedup vs baseline: 1.2734x; 1.0661x over previous
//
#include <hip/hip_runtime.h>
#include <hip/hip_bf16.h>

#define Bsz 256
#define Tlen 512
#define Dd 512
#define Hh 1024
#define G4 4096
#define NOUT 8
#define BT (Bsz * Tlen)

typedef short s16x8 __attribute__((ext_vector_type(8)));
typedef unsigned short u16x8 __attribute__((ext_vector_type(8)));
typedef float f32x4 __attribute__((ext_vector_type(4)));

__device__ __forceinline__ ushort f2bf(float f) {
    union { float f; uint u; } v; v.f = f;
    uint u = v.u;
    uint r = u + 0x7FFFu + ((u >> 16) & 1u);   // round-to-nearest-even
    return (ushort)(r >> 16);
}
__device__ __forceinline__ float bf2f(ushort u) {
    union { uint u; float f; } v; v.u = ((uint)u) << 16; return v.f;
}
__device__ __forceinline__ float sigf(float x) { return 1.f / (1.f + __expf(-x)); }
__device__ __forceinline__ float tanhfast(float x) {
    float ax = fabsf(x);
    float e = __expf(-2.f * ax);
    float t = (1.f - e) / (1.f + e);
    return copysignf(t, x);
}
__device__ __forceinline__ void gload16(const void* g, void* l) {
    __builtin_amdgcn_global_load_lds(
        (const __attribute__((address_space(1))) uint*)g,
        (__attribute__((address_space(3))) uint*)l, 16, 0, 0);
}

// ---------------- init: zero h0 (bf16, buffer 0) and c (fp32) ----------------
__global__ void init_kernel(uint4* __restrict__ h0, uint4* __restrict__ c) {
    int i = blockIdx.x * 256 + threadIdx.x;       // 65536 threads
    uint4 z = make_uint4(0u, 0u, 0u, 0u);
    c[i] = z;                                     // 1 MB
    if (i < 32768) h0[i] = z;                     // 512 KB
}

// ---------------- fp32 -> bf16 convert (layout-preserving) ----------------
__global__ void cvt_kernel(const float4* __restrict__ src, ushort4* __restrict__ dst, int n4) {
    int i = blockIdx.x * 256 + threadIdx.x;
    if (i >= n4) return;
    float4 v = src[i];
    ushort4 o;
    o.x = f2bf(v.x); o.y = f2bf(v.y); o.z = f2bf(v.z); o.w = f2bf(v.w);
    dst[i] = o;
}

// ---------------- chunk convert: x[:, t0..t0+7, :] fp32 -> [256][8][512] bf16 ----------------
__global__ void cvt_xchunk(const float* __restrict__ x, ushort* __restrict__ dst, int t0) {
    int gid = blockIdx.x * 256 + threadIdx.x;     // 131072 units of 8 elems
    int k8  = gid & 63;
    int tl  = (gid >> 6) & 7;
    int row = gid >> 9;                           // 0..255
    const float* s = x + ((size_t)row * Tlen + t0 + tl) * Dd + k8 * 8;
    float4 v0 = *(const float4*)s;
    float4 v1 = *(const float4*)(s + 4);
    u16x8 o;
    o[0]=f2bf(v0.x); o[1]=f2bf(v0.y); o[2]=f2bf(v0.z); o[3]=f2bf(v0.w);
    o[4]=f2bf(v1.x); o[5]=f2bf(v1.y); o[6]=f2bf(v1.z); o[7]=f2bf(v1.w);
    *(u16x8*)(dst + ((size_t)row * 8 + tl) * Dd + k8 * 8) = o;
}

// ---------------- one LSTM time step: wave-private staging, ZERO K-loop barriers ----
// 256 blocks x 512 threads (8 waves). Block -> (bt, jt) XCD-remap.
// Output tile 64 batch rows x 64 gate-cols. Wave w owns K-slice
// [w*192, (w+1)*192) = 6 chunks of K=32; stages A[64x32] + B[64x32] into its
// PRIVATE 16 KB LDS region (2 bufs) via global_load_lds, consumes them itself:
// the only hazard is its own vmcnt -> no workgroup barriers until the
// partial-reduce epilogue. Depth-2 prefetch, vmcnt(8) per chunk.
// Per-chunk ds_read_b128 pattern covers each 1 KB sub-block exactly once
// (64 distinct 16B chunks) -> conflict-free without swizzle.
__launch_bounds__(512)
__global__ void lstm_step6(const ushort* __restrict__ xsrc, int tstride, int tloc,
                           const ushort* __restrict__ Wih,   // bf16 [4096][512]
                           const ushort* __restrict__ Whh,   // bf16 [4096][1024]
                           const ushort* __restrict__ h_prev,// bf16 [256][1024]
                           ushort* __restrict__ h_next,
                           float* __restrict__ c,            // fp32 [256][1024]
                           const float* __restrict__ b_ih,
                           const float* __restrict__ b_hh) {
    __shared__ char smem[139264];        // tiles: 8 x 16 KB; epilogue: 8 x [64][68] f32
    __shared__ float bias_lds[64];

    const int tid  = threadIdx.x;
    const int lane = tid & 63;
    const int w    = tid >> 6;           // 0..7
    const int B    = blockIdx.x;
    const int xcd  = B & 7, slot = B >> 3;     // XCD remap: 4 bt-copies of a jt share an XCD
    const int jt   = xcd * 8 + (slot >> 2);    // 0..63
    const int bt   = slot & 3;                 // 0..3
    const int b0   = bt * 64;

    if (tid < 64) {
        int gcol = (tid >> 4) * 1024 + jt * 16 + (tid & 15);
        bias_lds[tid] = b_ih[gcol] + b_hh[gcol];
    }

    char* reg = smem + w * 16384;        // wave-private region
    const int rlo   = lane & 15;
    const int off16 = (lane >> 4) << 4;  // byte offset of k-oct within a row
    const int lrow  = lane >> 2;         // 0..15 (staging row within 16-row group)
    const int lke   = (lane & 3) << 3;   // 0,8,16,24 elements

    // stage chunk ch (wave-local k = ch*32) into buf: 4 A-gloads + 4 B-gloads.
    auto STAGE = [&](int buf, int ch) {
        const int k0 = w * 192 + (ch << 5);      // global k
        char* Ab = reg + buf * 8192;
        char* Bb = Ab + 4096;
        #pragma unroll
        for (int q = 0; q < 4; ++q) {
            const int row = (q << 4) + lrow;
            // A: batch rows (x for k0<512, h for k0>=512)
            const ushort* pa = (k0 < Dd)
                ? xsrc + ((size_t)(b0 + row) * tstride + tloc) * Dd + k0 + lke
                : h_prev + (size_t)(b0 + row) * Hh + (k0 - Dd) + lke;
            gload16(pa, Ab + (q << 10));
            // B: gate cols; col = q*16 + lrow -> grow = q*1024 + jt*16 + lrow
            const int grow = (q << 10) + (jt << 4) + lrow;
            const ushort* pb = (k0 < Dd)
                ? Wih + (size_t)grow * Dd + k0 + lke
                : Whh + (size_t)grow * Hh + (k0 - Dd) + lke;
            gload16(pb, Bb + (q << 10));
        }
    };

    f32x4 acc[4][4] = {};

    STAGE(0, 0);
    STAGE(1, 1);
    #pragma unroll
    for (int ch = 0; ch < 6; ++ch) {
        const int buf = ch & 1;
        if (ch < 5) {
            asm volatile("s_waitcnt vmcnt(8)" ::: "memory");   // chunk ch landed, ch+1 in flight
        } else {
            asm volatile("s_waitcnt vmcnt(0)" ::: "memory");
        }
        __builtin_amdgcn_sched_barrier(0);
        const char* Ab = reg + buf * 8192;
        const char* Bb = Ab + 4096;
        s16x8 bfr[4], a[4];
        #pragma unroll
        for (int n = 0; n < 4; ++n)
            bfr[n] = *(const s16x8*)(Bb + (((n << 4) + rlo) << 6) + off16);
        #pragma unroll
        for (int m = 0; m < 4; ++m)
            a[m] = *(const s16x8*)(Ab + (((m << 4) + rlo) << 6) + off16);
        if (ch < 4) {
            asm volatile("s_waitcnt lgkmcnt(0)" ::: "memory"); // my reads done -> buf reusable
            __builtin_amdgcn_sched_barrier(0);
            STAGE(buf, ch + 2);
        }
        #pragma unroll
        for (int m = 0; m < 4; ++m)
            #pragma unroll
            for (int n = 0; n < 4; ++n)
                acc[m][n] = __builtin_amdgcn_mfma_f32_16x16x32_bf16(a[m], bfr[n], acc[m][n], 0, 0, 0);
    }

    __syncthreads();                     // all waves done computing; LDS free for partials

    // ---- partial tile -> LDS (2 lanes/bank worst case = free) ----
    float* part = (float*)smem;          // 8 x [64][68]
    float* bw = part + w * (64 * 68);
    {
        const int q4 = (lane >> 4) << 2;
        #pragma unroll
        for (int m = 0; m < 4; ++m)
            #pragma unroll
            for (int n = 0; n < 4; ++n)
                #pragma unroll
                for (int j = 0; j < 4; ++j) {
                    int row = (m << 4) + q4 + j;
                    int col = (n << 4) + rlo;
                    bw[row * 68 + col] = acc[m][n][j];
                }
    }
    __syncthreads();

    // ---- reduce 8 partials + activations + cell update ----
    const int cv = tid & 15;
    const int r0 = (tid >> 4) << 1;
    #pragma unroll
    for (int u = 0; u < 2; ++u) {
        const int row = r0 + u;
        float gi = bias_lds[cv],      gf = bias_lds[16 + cv];
        float gg = bias_lds[32 + cv], go = bias_lds[48 + cv];
        #pragma unroll
        for (int p = 0; p < 8; ++p) {
            const float* bb = part + p * (64 * 68) + row * 68;
            gi += bb[cv]; gf += bb[16 + cv]; gg += bb[32 + cv]; go += bb[48 + cv];
        }
        float i_ = sigf(gi), f_ = sigf(gf), g_ = tanhfast(gg), o_ = sigf(go);
        const int gcol = (jt << 4) + cv;
        const size_t cidx = (size_t)(b0 + row) * Hh + gcol;
        float cn = f_ * c[cidx] + i_ * g_;
        c[cidx] = cn;
        h_next[cidx] = f2bf(o_ * tanhfast(cn));
    }
}

// ---------------- FALLBACK: proven round-0 fused step ----------------
__launch_bounds__(256)
__global__ void lstm_step_fused(const float* __restrict__ x,
                          const ushort* __restrict__ Wih,
                          const ushort* __restrict__ Whh,
                          const float* __restrict__ b_ih,
                          const float* __restrict__ b_hh,
                          const ushort* __restrict__ h_prev,
                          ushort* __restrict__ h_next,
                          float* __restrict__ c,
                          int t) {
    __shared__ ushort At[64 * 64];
    __shared__ ushort Bt[64 * 64];
    __shared__ float gates[64 * 72];

    const int tid  = threadIdx.x;
    const int lane = tid & 63;
    const int wid  = tid >> 6;
    const int wr   = wid >> 1;
    const int wc   = wid & 1;
    const int bt   = blockIdx.x >> 6;
    const int jt   = blockIdx.x & 63;
    const int b0   = bt * 64;
    const int j0   = jt * 16;

    f32x4 acc[2][2] = {};

    auto mfma_tile = [&]() {
        #pragma unroll
        for (int ks = 0; ks < 2; ++ks) {
            const int kc = (ks << 2) + (lane >> 4);
            s16x8 a[2], bfr[2];
            #pragma unroll
            for (int m = 0; m < 2; ++m) {
                int row = wr * 32 + m * 16 + (lane & 15);
                a[m] = *(const s16x8*)&At[row * 64 + ((kc ^ (row & 7)) << 3)];
            }
            #pragma unroll
            for (int n = 0; n < 2; ++n) {
                int col = wc * 32 + n * 16 + (lane & 15);
                bfr[n] = *(const s16x8*)&Bt[col * 64 + ((kc ^ (col & 7)) << 3)];
            }
            #pragma unroll
            for (int m = 0; m < 2; ++m)
                #pragma unroll
                for (int n = 0; n < 2; ++n)
                    acc[m][n] = __builtin_amdgcn_mfma_f32_16x16x32_bf16(a[m], bfr[n], acc[m][n], 0, 0, 0);
        }
    };

    for (int kb = 0; kb < Dd; kb += 64) {
        __syncthreads();
        #pragma unroll
        for (int it = 0; it < 4; ++it) {
            int idx = tid + it * 256;
            int row = idx >> 4;
            int k   = (idx & 15) * 4;
            const float4 v = *(const float4*)&x[(size_t)(b0 + row) * (Tlen * Dd) + (size_t)t * Dd + kb + k];
            ushort4 o;
            o.x = f2bf(v.x); o.y = f2bf(v.y); o.z = f2bf(v.z); o.w = f2bf(v.w);
            int dst = row * 64 + (((k >> 3) ^ (row & 7)) << 3) + (k & 7);
            *(ushort4*)&At[dst] = o;
        }
        #pragma unroll
        for (int it = 0; it < 2; ++it) {
            int idx = tid + it * 256;
            int col = idx >> 3;
            int kc  = idx & 7;
            int grow = ((col >> 4) << 10) + j0 + (col & 15);
            uint4 v = *(const uint4*)&Wih[(size_t)grow * Dd + kb + kc * 8];
            *(uint4*)&Bt[col * 64 + ((kc ^ (col & 7)) << 3)] = v;
        }
        __syncthreads();
        mfma_tile();
    }
    for (int kb = 0; kb < Hh; kb += 64) {
        __syncthreads();
        #pragma unroll
        for (int it = 0; it < 2; ++it) {
            int idx = tid + it * 256;
            int row = idx >> 3;
            int kc  = idx & 7;
            uint4 v = *(const uint4*)&h_prev[(size_t)(b0 + row) * Hh + kb + kc * 8];
            *(uint4*)&At[row * 64 + ((kc ^ (row & 7)) << 3)] = v;
        }
        #pragma unroll
        for (int it = 0; it < 2; ++it) {
            int idx = tid + it * 256;
            int col = idx >> 3;
            int kc  = idx & 7;
            int grow = ((col >> 4) << 10) + j0 + (col & 15);
            uint4 v = *(const uint4*)&Whh[(size_t)grow * Hh + kb + kc * 8];
            *(uint4*)&Bt[col * 64 + ((kc ^ (col & 7)) << 3)] = v;
        }
        __syncthreads();
        mfma_tile();
    }

    #pragma unroll
    for (int m = 0; m < 2; ++m)
        #pragma unroll
        for (int n = 0; n < 2; ++n)
            #pragma unroll
            for (int j = 0; j < 4; ++j) {
                int row = wr * 32 + m * 16 + ((lane >> 4) << 2) + j;
                int col = wc * 32 + n * 16 + (lane & 15);
                gates[row * 72 + col] = acc[m][n][j];
            }
    __syncthreads();

    #pragma unroll
    for (int it = 0; it < 4; ++it) {
        int idx = tid + it * 256;
        int row = idx >> 4;
        int cc  = idx & 15;
        int gcol = j0 + cc;
        float gi = gates[row * 72 + cc]      + b_ih[gcol]          + b_hh[gcol];
        float gf = gates[row * 72 + 16 + cc] + b_ih[Hh + gcol]     + b_hh[Hh + gcol];
        float gg = gates[row * 72 + 32 + cc] + b_ih[2 * Hh + gcol] + b_hh[2 * Hh + gcol];
        float go = gates[row * 72 + 48 + cc] + b_ih[3 * Hh + gcol] + b_hh[3 * Hh + gcol];
        float i_ = sigf(gi);
        float f_ = sigf(gf);
        float g_ = tanhfast(gg);
        float o_ = sigf(go);
        size_t cidx = (size_t)(b0 + row) * Hh + gcol;
        float cn = f_ * c[cidx] + i_ * g_;
        c[cidx] = cn;
        float hn = o_ * tanhfast(cn);
        h_next[cidx] = f2bf(hn);
    }
}

// ---------------- FC head ----------------
__global__ void fc_kernel(const ushort* __restrict__ h,
                          const float* __restrict__ Wfc,
                          const float* __restrict__ bfc,
                          float* __restrict__ out) {
    int b = blockIdx.x;
    int w = threadIdx.x >> 6;
    int lane = threadIdx.x & 63;
    float s = 0.f;
    for (int k = lane; k < Hh; k += 64)
        s += bf2f(h[(size_t)b * Hh + k]) * Wfc[w * Hh + k];
    #pragma unroll
    for (int off = 32; off; off >>= 1) s += __shfl_down(s, off);
    if (lane == 0) out[b * NOUT + w] = sigf(s + bfc[w]);
}

// ================= LAUNCH =================

extern "C" void kernel_launch(void* const* d_in, const int* in_sizes, int n_in,
                              void* d_out, int out_size, void* d_ws, size_t ws_size,
                              hipStream_t stream) {
    const float* x    = (const float*)d_in[0];
    const float* W_ih = (const float*)d_in[1];
    const float* W_hh = (const float*)d_in[2];
    const float* b_ih = (const float*)d_in[3];
    const float* b_hh = (const float*)d_in[4];
    const float* W_fc = (const float*)d_in[5];
    const float* b_fc = (const float*)d_in[6];
    float* out = (float*)d_out;
    char* ws = (char*)d_ws;

    // ws layout (fixed part = 14 MB, proven available):
    //   [0, 1 MB)    h ping-pong bf16 [2][256][1024]
    //   [1, 2 MB)    c fp32 [256][1024]
    //   [2, 6 MB)    W_ih bf16 [4096][512]
    //   [6, 14 MB)   W_hh bf16 [4096][1024]
    //   [14 MB, ..)  x bf16: full [256][512][512] (128 MB, T1) or
    //                2 chunk buffers [256][8][512] (4 MB, T2)
    ushort* h_buf  = (ushort*)ws;
    float*  c_ws   = (float*)(ws + (1ull << 20));
    ushort* wih_bf = (ushort*)(ws + (2ull << 20));
    ushort* whh_bf = (ushort*)(ws + (6ull << 20));
    char*   x_ext  = ws + (14ull << 20);

    const size_t FIXED   = 14ull << 20;
    const size_t XFULL   = (size_t)Bsz * Tlen * Dd * 2;        // 128 MB
    const size_t XCHUNK  = (size_t)Bsz * 8 * Dd * 2;           // 2 MB per buffer

    init_kernel<<<256, 256, 0, stream>>>((uint4*)h_buf, (uint4*)c_ws);
    cvt_kernel<<<(G4 * Dd / 4) / 256, 256, 0, stream>>>((const float4*)W_ih, (ushort4*)wih_bf, G4 * Dd / 4);
    cvt_kernel<<<(G4 * Hh / 4) / 256, 256, 0, stream>>>((const float4*)W_hh, (ushort4*)whh_bf, G4 * Hh / 4);

    if (ws_size >= FIXED + XFULL) {
        // T1: convert all of x once; layout [b][t][k] (tstride=512)
        ushort* x_bf = (ushort*)x_ext;
        const int n4 = BT * Dd / 4;
        cvt_kernel<<<n4 / 256, 256, 0, stream>>>((const float4*)x, (ushort4*)x_bf, n4);
        for (int t = 0; t < Tlen; ++t) {
            const ushort* hp = h_buf + (size_t)(t & 1) * Bsz * Hh;
            ushort*       hn = h_buf + (size_t)((t + 1) & 1) * Bsz * Hh;
            lstm_step6<<<256, 512, 0, stream>>>(x_bf, Tlen, t, wih_bf, whh_bf,
                                                hp, hn, c_ws, b_ih, b_hh);
        }
    } else if (ws_size >= FIXED + 2 * XCHUNK) {
        // T2: double-buffered 8-step chunks; layout [b][8][k] (tstride=8)
        ushort* xchunk = (ushort*)x_ext;
        for (int t = 0; t < Tlen; ++t) {
            if ((t & 7) == 0) {
                ushort* dst = xchunk + (size_t)((t >> 3) & 1) * (Bsz * 8 * Dd);
                cvt_xchunk<<<512, 256, 0, stream>>>(x, dst, t);
            }
            const ushort* xb = xchunk + (size_t)((t >> 3) & 1) * (Bsz * 8 * Dd);
            const ushort* hp = h_buf + (size_t)(t & 1) * Bsz * Hh;
            ushort*       hn = h_buf + (size_t)((t + 1) & 1) * Bsz * Hh;
            lstm_step6<<<256, 512, 0, stream>>>(xb, 8, t & 7, wih_bf, whh_bf,
                                                hp, hn, c_ws, b_ih, b_hh);
        }
    } else {
        // T3: proven fallback
        for (int t = 0; t < Tlen; ++t) {
            const ushort* hp = h_buf + (size_t)(t & 1) * Bsz * Hh;
            ushort*       hn = h_buf + (size_t)((t + 1) & 1) * Bsz * Hh;
            lstm_step_fused<<<256, 256, 0, stream>>>(x, wih_bf, whh_bf, b_ih, b_hh, hp, hn, c_ws, t);
        }
    }
    // 512 steps (even) -> final h in buffer 0
    fc_kernel<<<256, 512, 0, stream>>>(h_buf, W_fc, b_fc, out);
}